// Round 1
// baseline (281.871 us; speedup 1.0000x reference)
//
#include <hip/hip_runtime.h>
#include <cmath>

#pragma clang fp contract(off)

#define BB 32
#define QQ 2000
#define GG 64
#define CCH 80
#define NT 1024
#define NW 16

// ---------------------------------------------------------------------------
// Kernel 1: build cost matrix in [b][g][q] layout (column-contiguous).
// cost = 5*L1(norm boxes) + 2*focal_class + 2*(-giou) + 100*(~in_bc) + (!fg)*1e4
// ---------------------------------------------------------------------------
__global__ void cost_kernel(const float* __restrict__ logits,
                            const float* __restrict__ boxes,
                            const int* __restrict__ gtc,
                            const float* __restrict__ gtb,
                            const float* __restrict__ szout,
                            const float* __restrict__ sztgt,
                            float* __restrict__ cost) {
#pragma clang fp contract(off)
  const int b = blockIdx.y;
  const int q = blockIdx.x * blockDim.x + threadIdx.x;
  __shared__ float sg0[GG], sg1[GG], sg2[GG], sg3[GG];
  __shared__ float st0[GG], st1[GG], st2[GG], st3[GG];
  __shared__ float sarea[GG], scxlo[GG], scxhi[GG], scylo[GG], scyhi[GG];
  __shared__ int scls[GG];
  if (threadIdx.x < GG) {
    int g = threadIdx.x;
    int base = (b * GG + g) << 2;
    float g0 = gtb[base + 0], g1 = gtb[base + 1], g2 = gtb[base + 2], g3 = gtb[base + 3];
    sg0[g] = g0; sg1[g] = g1; sg2[g] = g2; sg3[g] = g3;
    st0[g] = g0 / sztgt[base + 0];
    st1[g] = g1 / sztgt[base + 1];
    st2[g] = g2 / sztgt[base + 2];
    st3[g] = g3 / sztgt[base + 3];
    sarea[g] = (g2 - g0) * (g3 - g1);
    float gcx = (g0 + g2) * 0.5f, gcy = (g1 + g3) * 0.5f;
    float gw = g2 - g0, gh = g3 - g1;
    scxlo[g] = gcx - 2.5f * gw; scxhi[g] = gcx + 2.5f * gw;
    scylo[g] = gcy - 2.5f * gh; scyhi[g] = gcy + 2.5f * gh;
    scls[g] = gtc[b * GG + g];
  }
  __syncthreads();
  if (q >= QQ) return;

  float4 bx = reinterpret_cast<const float4*>(boxes)[b * QQ + q];
  float x1 = bx.x, y1 = bx.y, x2 = bx.z, y2 = bx.w;
  float on0 = x1 / szout[b * 4 + 0], on1 = y1 / szout[b * 4 + 1];
  float on2 = x2 / szout[b * 4 + 2], on3 = y2 / szout[b * 4 + 3];
  float cx = (x1 + x2) * 0.5f, cy = (y1 + y2) * 0.5f;
  float areaa = (x2 - x1) * (y2 - y1);

  // pass 1: fg_mask + in_bc bits
  unsigned long long inbc = 0ull;
  bool anyb = false, anyc = false;
  for (int g = 0; g < GG; ++g) {
    bool ib = (cx > sg0[g]) & (cx < sg2[g]) & (cy > sg1[g]) & (cy < sg3[g]);
    bool ic = (cx > scxlo[g]) & (cx < scxhi[g]) & (cy > scylo[g]) & (cy < scyhi[g]);
    anyb |= ib; anyc |= ic;
    if (ib & ic) inbc |= (1ull << g);
  }
  float fgadd = (anyb | anyc) ? 0.0f : 1e4f;

  const float* lrow = logits + (size_t)(b * QQ + q) * CCH;
  float* crow = cost + (size_t)b * GG * QQ + q;
  for (int g = 0; g < GG; ++g) {
    // iou / union
    float ltx = fmaxf(x1, sg0[g]), lty = fmaxf(y1, sg1[g]);
    float rbx = fminf(x2, sg2[g]), rby = fminf(y2, sg3[g]);
    float iw = fmaxf(rbx - ltx, 0.0f), ih = fmaxf(rby - lty, 0.0f);
    float inter = iw * ih;
    float uni = (areaa + sarea[g]) - inter;
    float iou = inter / uni;
    // enclosing box -> giou
    float ex1 = fminf(x1, sg0[g]), ey1 = fminf(y1, sg1[g]);
    float ex2 = fmaxf(x2, sg2[g]), ey2 = fmaxf(y2, sg3[g]);
    float ew = fmaxf(ex2 - ex1, 0.0f), eh = fmaxf(ey2 - ey1, 0.0f);
    float areac = ew * eh;
    float giou = iou - (areac - uni) / areac;
    // focal class cost at gt class
    float p = lrow[scls[g]];
    float negc = (0.75f * (p * p)) * (-logf((1.0f - p) + 1e-8f));
    float posc = (0.25f * ((1.0f - p) * (1.0f - p))) * (-logf(p + 1e-8f));
    float ccls = posc - negc;
    // L1 bbox (normalized), left-assoc like the reference reduce
    float cb = ((fabsf(on0 - st0[g]) + fabsf(on1 - st1[g])) + fabsf(on2 - st2[g])) + fabsf(on3 - st3[g]);
    float notbc = ((inbc >> g) & 1ull) ? 0.0f : 1.0f;
    float c = ((5.0f * cb + 2.0f * ccls) + 2.0f * (-giou)) + 100.0f * notbc;
    c = c + fgadd;
    crow[(size_t)g * QQ] = c;
  }
}

// ---------------------------------------------------------------------------
// Kernel 2: per-batch dynamic-k matching. One block (1024 thr = 16 waves)
// per batch item. Match bits live in LDS (2x u32 per query). All argmins use
// (value, index) lexicographic order = stable-argsort / jnp.argmin semantics.
// ---------------------------------------------------------------------------
__global__ __launch_bounds__(NT) void match_kernel(const float* __restrict__ boxes,
                                                   const float* __restrict__ gtb,
                                                   const float* __restrict__ cost,
                                                   float* __restrict__ out_match,
                                                   float* __restrict__ out_ids) {
#pragma clang fp contract(off)
  const int b = blockIdx.x;
  const int tid = threadIdx.x;
  const int w = tid >> 6;
  const int lane = tid & 63;

  __shared__ unsigned s_mlo[QQ], s_mhi[QQ];
  __shared__ unsigned short s_kpen[QQ];
  __shared__ float s_g0[GG], s_g1[GG], s_g2[GG], s_g3[GG], s_ga[GG];
  __shared__ int s_addq[GG];
  __shared__ unsigned s_rlo[NW], s_rhi[NW];
  __shared__ unsigned s_gmlo, s_gmhi;
  __shared__ int s_anyun;

  for (int q = tid; q < QQ; q += NT) { s_mlo[q] = 0u; s_mhi[q] = 0u; s_kpen[q] = 0; }
  if (tid < GG) {
    int g = tid;
    int base = (b * GG + g) << 2;
    float g0 = gtb[base + 0], g1 = gtb[base + 1], g2 = gtb[base + 2], g3 = gtb[base + 3];
    s_g0[g] = g0; s_g1[g] = g1; s_g2[g] = g2; s_g3[g] = g3;
    s_ga[g] = (g2 - g0) * (g3 - g1);
  }
  __syncthreads();

  const float* costb = cost + (size_t)b * GG * QQ;

  // ---- Phase A+B: per-column dynamic_k (top-5 iou sum) then k-smallest cost
  for (int col = w; col < GG; col += NW) {
    float v[32];
    float gx1 = s_g0[col], gy1 = s_g1[col], gx2 = s_g2[col], gy2 = s_g3[col], ga = s_ga[col];
    #pragma unroll
    for (int j = 0; j < 32; ++j) {
      int q = lane + (j << 6);
      if (q < QQ) {
        float4 bx = reinterpret_cast<const float4*>(boxes)[b * QQ + q];
        float areaa = (bx.z - bx.x) * (bx.w - bx.y);
        float ltx = fmaxf(bx.x, gx1), lty = fmaxf(bx.y, gy1);
        float rbx = fminf(bx.z, gx2), rby = fminf(bx.w, gy2);
        float iw = fmaxf(rbx - ltx, 0.0f), ih = fmaxf(rby - lty, 0.0f);
        float inter = iw * ih;
        v[j] = inter / ((areaa + ga) - inter);
      } else v[j] = -1.0f;
    }
    unsigned rm = 0u;
    float s = 0.0f;
    for (int pass = 0; pass < 5; ++pass) {
      float bv = -1e30f; int bq = 0x7fffffff;
      #pragma unroll
      for (int j = 0; j < 32; ++j) {
        int q = lane + (j << 6);
        if (q < QQ && !((rm >> j) & 1u) && v[j] > bv) { bv = v[j]; bq = q; }
      }
      for (int off = 32; off; off >>= 1) {
        float ov = __shfl_down(bv, off, 64); int oq = __shfl_down(bq, off, 64);
        if (ov > bv || (ov == bv && oq < bq)) { bv = ov; bq = oq; }
      }
      bv = __shfl(bv, 0, 64); bq = __shfl(bq, 0, 64);
      s += bv;                              // descending order, left-assoc (top_k sum)
      if ((bq & 63) == lane) rm |= (1u << (bq >> 6));
    }
    int dynk = (int)s;                      // trunc toward zero, like astype(int32)
    if (dynk < 1) dynk = 1;

    // k smallest costs in this column (stable: first-index tie-break)
    const float* ccol = costb + (size_t)col * QQ;
    #pragma unroll
    for (int j = 0; j < 32; ++j) {
      int q = lane + (j << 6);
      v[j] = (q < QQ) ? ccol[q] : 0.0f;
    }
    rm = 0u;
    int picks[5];
    for (int pass = 0; pass < 5; ++pass) {
      float bv = INFINITY; int bq = 0x7fffffff;
      #pragma unroll
      for (int j = 0; j < 32; ++j) {
        int q = lane + (j << 6);
        if (q < QQ && !((rm >> j) & 1u) && v[j] < bv) { bv = v[j]; bq = q; }
      }
      for (int off = 32; off; off >>= 1) {
        float ov = __shfl_down(bv, off, 64); int oq = __shfl_down(bq, off, 64);
        if (ov < bv || (ov == bv && oq < bq)) { bv = ov; bq = oq; }
      }
      bq = __shfl(bq, 0, 64);
      picks[pass] = bq;
      if ((bq & 63) == lane) rm |= (1u << (bq >> 6));
    }
    if (lane == 0) {
      #pragma unroll
      for (int i = 0; i < 5; ++i) if (i < dynk) {
        int q = picks[i];
        if (col < 32) atomicOr(&s_mlo[q], 1u << col);
        else          atomicOr(&s_mhi[q], 1u << (col - 32));
      }
    }
  }
  __syncthreads();

  // ---- initial dedup: over-queries -> one-hot at row argmin (original cost)
  for (int q = tid; q < QQ; q += NT) {
    if (__popc(s_mlo[q]) + __popc(s_mhi[q]) > 1) {
      float bv = INFINITY; int bg = 0;
      for (int g = 0; g < GG; ++g) {
        float cv = costb[(size_t)g * QQ + q];
        if (cv < bv) { bv = cv; bg = g; }
      }
      s_mlo[q] = (bg < 32) ? (1u << bg) : 0u;
      s_mhi[q] = (bg >= 32) ? (1u << (bg - 32)) : 0u;
    }
  }
  __syncthreads();

  // ---- main loop (fori_loop 0..G). Early exit == reference identity body.
  for (int iter = 0; iter < GG; ++iter) {
    // 1. which gts are matched (OR-reduce masks)
    unsigned lo = 0u, hi = 0u;
    for (int q = tid; q < QQ; q += NT) { lo |= s_mlo[q]; hi |= s_mhi[q]; }
    for (int off = 32; off; off >>= 1) { lo |= __shfl_down(lo, off, 64); hi |= __shfl_down(hi, off, 64); }
    if (lane == 0) { s_rlo[w] = lo; s_rhi[w] = hi; }
    __syncthreads();
    if (tid == 0) {
      unsigned L = 0u, H = 0u;
      for (int i = 0; i < NW; ++i) { L |= s_rlo[i]; H |= s_rhi[i]; }
      s_gmlo = L; s_gmhi = H;
      s_anyun = (L != 0xffffffffu) || (H != 0xffffffffu);
    }
    __syncthreads();
    if (!s_anyun) break;
    unsigned gmlo = s_gmlo, gmhi = s_gmhi;

    // 2. penalty count for queries matched at iteration start (+1e5 applied)
    for (int q = tid; q < QQ; q += NT) if (s_mlo[q] | s_mhi[q]) s_kpen[q]++;

    // 3. per unmatched gt: argmin over unmatched queries (penalized never win)
    for (int col = w; col < GG; col += NW) {
      bool matched = (col < 32) ? ((gmlo >> col) & 1u) : ((gmhi >> (col - 32)) & 1u);
      if (matched) continue;
      const float* ccol = costb + (size_t)col * QQ;
      float bv = INFINITY; int bq = 0x7fffffff;
      for (int q = lane; q < QQ; q += 64) {
        if ((s_mlo[q] | s_mhi[q]) == 0u) {
          float cv = ccol[q];
          if (cv < bv) { bv = cv; bq = q; }
        }
      }
      for (int off = 32; off; off >>= 1) {
        float ov = __shfl_down(bv, off, 64); int oq = __shfl_down(bq, off, 64);
        if (ov < bv || (ov == bv && oq < bq)) { bv = ov; bq = oq; }
      }
      if (lane == 0) s_addq[col] = bq;
    }
    __syncthreads();

    // 4. apply adds (same query may serve several gts -> atomic)
    if (tid < GG) {
      bool matched = (tid < 32) ? ((gmlo >> tid) & 1u) : ((gmhi >> (tid - 32)) & 1u);
      if (!matched) {
        int q = s_addq[tid];
        if (tid < 32) atomicOr(&s_mlo[q], 1u << tid);
        else          atomicOr(&s_mhi[q], 1u << (tid - 32));
      }
    }
    __syncthreads();

    // 5. dedup: over rows are freshly-added (unpenalized) -> original cost row
    for (int q = tid; q < QQ; q += NT) {
      if (__popc(s_mlo[q]) + __popc(s_mhi[q]) > 1) {
        float bv = INFINITY; int bg = 0;
        for (int g = 0; g < GG; ++g) {
          float cv = costb[(size_t)g * QQ + q];
          if (cv < bv) { bv = cv; bg = g; }
        }
        s_mlo[q] = (bg < 32) ? (1u << bg) : 0u;
        s_mhi[q] = (bg >= 32) ? (1u << (bg - 32)) : 0u;
      }
    }
    __syncthreads();
  }

  // ---- matched_query_id FIRST (cost may alias the matching output region).
  // Exact FP penalty chain: ((c+1e5)+1e5)+... k times, matching the reference.
  for (int col = w; col < GG; col += NW) {
    const float* ccol = costb + (size_t)col * QQ;
    float bv = INFINITY; int bq = 0x7fffffff;
    for (int q = lane; q < QQ; q += 64) {
      unsigned m = (col < 32) ? s_mlo[q] : s_mhi[q];
      if ((m >> (col & 31)) & 1u) {
        float cv = ccol[q];
        int k = s_kpen[q];
        for (int t = 0; t < k; ++t) cv += 1e5f;
        if (cv < bv) { bv = cv; bq = q; }
      }
    }
    for (int off = 32; off; off >>= 1) {
      float ov = __shfl_down(bv, off, 64); int oq = __shfl_down(bq, off, 64);
      if (ov < bv || (ov == bv && oq < bq)) { bv = ov; bq = oq; }
    }
    if (lane == 0) out_ids[b * GG + col] = (float)((bq == 0x7fffffff) ? 0 : bq);
  }
  __syncthreads();

  // ---- matching matrix [Q,G] (coalesced; overwrites this block's cost slab
  // only after all reads are done)
  float* om = out_match + (size_t)b * QQ * GG;
  for (int idx = tid; idx < QQ * GG; idx += NT) {
    int q = idx >> 6, g = idx & 63;
    unsigned m = (g < 32) ? s_mlo[q] : s_mhi[q];
    om[idx] = ((m >> (g & 31)) & 1u) ? 1.0f : 0.0f;
  }
}

extern "C" void kernel_launch(void* const* d_in, const int* in_sizes, int n_in,
                              void* d_out, int out_size, void* d_ws, size_t ws_size,
                              hipStream_t stream) {
  const float* logits = (const float*)d_in[0];
  const float* boxes  = (const float*)d_in[1];
  const int*   gtc    = (const int*)d_in[2];
  const float* gtbx   = (const float*)d_in[3];
  const float* szout  = (const float*)d_in[4];
  const float* sztgt  = (const float*)d_in[5];
  float* out = (float*)d_out;

  size_t need = (size_t)BB * GG * QQ * sizeof(float);
  // Prefer workspace; if it's too small, stage cost in the matching output
  // region (match_kernel computes ids before overwriting it).
  float* cost = (ws_size >= need) ? (float*)d_ws : out;

  dim3 g1((QQ + 255) / 256, BB);
  hipLaunchKernelGGL(cost_kernel, g1, dim3(256), 0, stream,
                     logits, boxes, gtc, gtbx, szout, sztgt, cost);
  hipLaunchKernelGGL(match_kernel, dim3(BB), dim3(NT), 0, stream,
                     boxes, gtbx, cost, out, out + (size_t)BB * QQ * GG);
}

// Round 2
// 165.734 us; speedup vs baseline: 1.7007x; 1.7007x over previous
//
#include <hip/hip_runtime.h>
#include <cmath>

#pragma clang fp contract(off)

#define BB 32
#define QQ 2000
#define GG 64
#define CCH 80

// ---------------------------------------------------------------------------
// K1: cost matrix in [b][g][q] layout + per-query row argmin.
// Orientation: lane = gt index, each wave processes 16 queries serially.
// The focal gather then reads ONE 320B logits row per q (≈5 cache lines for
// 64 lanes) instead of 64 scattered rows. Coalesced [g][q] store via LDS
// transpose (65-float pitch -> 2-way bank aliasing = free).
// ---------------------------------------------------------------------------
__global__ __launch_bounds__(256) void cost_kernel(
    const float* __restrict__ logits, const float* __restrict__ boxes,
    const int* __restrict__ gtc, const float* __restrict__ gtb,
    const float* __restrict__ szout, const float* __restrict__ sztgt,
    float* __restrict__ cost, int* __restrict__ rowarg) {
#pragma clang fp contract(off)
  const int b = blockIdx.y;
  const int q0 = blockIdx.x * 64;
  const int t = threadIdx.x;
  const int w = t >> 6, lane = t & 63;

  __shared__ float4 s_qb[64];
  __shared__ float s_tile[64 * 65];

  // per-lane (= per-gt) constants, all registers
  const int gbase = (b * GG + lane) * 4;
  const float g0 = gtb[gbase + 0], g1 = gtb[gbase + 1];
  const float g2 = gtb[gbase + 2], g3 = gtb[gbase + 3];
  const float t0 = g0 / sztgt[gbase + 0], t1 = g1 / sztgt[gbase + 1];
  const float t2 = g2 / sztgt[gbase + 2], t3 = g3 / sztgt[gbase + 3];
  const float garea = (g2 - g0) * (g3 - g1);
  const float gcx = (g0 + g2) * 0.5f, gcy = (g1 + g3) * 0.5f;
  const float gw = g2 - g0, gh = g3 - g1;
  const float cxlo = gcx - 2.5f * gw, cxhi = gcx + 2.5f * gw;
  const float cylo = gcy - 2.5f * gh, cyhi = gcy + 2.5f * gh;
  const int cls = gtc[b * GG + lane];
  const float so0 = szout[b * 4 + 0], so1 = szout[b * 4 + 1];
  const float so2 = szout[b * 4 + 2], so3 = szout[b * 4 + 3];

  if (t < 64) {
    int q = q0 + t;
    s_qb[t] = (q < QQ) ? reinterpret_cast<const float4*>(boxes)[b * QQ + q]
                       : make_float4(0.f, 0.f, 1.f, 1.f);
  }
  __syncthreads();

  const float* lbase = logits + (size_t)b * QQ * CCH;
  for (int i = 0; i < 16; ++i) {
    const int qi = w * 16 + i;      // wave-uniform query index
    const int q = q0 + qi;
    float4 bx = s_qb[qi];
    float x1 = bx.x, y1 = bx.y, x2 = bx.z, y2 = bx.w;
    float on0 = x1 / so0, on1 = y1 / so1, on2 = x2 / so2, on3 = y2 / so3;
    float cx = (x1 + x2) * 0.5f, cy = (y1 + y2) * 0.5f;
    float areaa = (x2 - x1) * (y2 - y1);

    bool ib = (cx > g0) & (cx < g2) & (cy > g1) & (cy < g3);
    bool ic = (cx > cxlo) & (cx < cxhi) & (cy > cylo) & (cy < cyhi);
    // any over gts == any over the wave's 64 lanes
    bool fg = (__ballot(ib) != 0ull) || (__ballot(ic) != 0ull);
    float fgadd = fg ? 0.0f : 1e4f;

    float ltx = fmaxf(x1, g0), lty = fmaxf(y1, g1);
    float rbx = fminf(x2, g2), rby = fminf(y2, g3);
    float iw = fmaxf(rbx - ltx, 0.0f), ih = fmaxf(rby - lty, 0.0f);
    float inter = iw * ih;
    float uni = (areaa + garea) - inter;
    float iou = inter / uni;
    float ex1 = fminf(x1, g0), ey1 = fminf(y1, g1);
    float ex2 = fmaxf(x2, g2), ey2 = fmaxf(y2, g3);
    float ew = fmaxf(ex2 - ex1, 0.0f), eh = fmaxf(ey2 - ey1, 0.0f);
    float areac = ew * eh;
    float giou = iou - (areac - uni) / areac;

    float p = (q < QQ) ? lbase[(size_t)q * CCH + cls] : 0.5f;
    float negc = (0.75f * (p * p)) * (-logf((1.0f - p) + 1e-8f));
    float posc = (0.25f * ((1.0f - p) * (1.0f - p))) * (-logf(p + 1e-8f));
    float ccls = posc - negc;

    float cb = ((fabsf(on0 - t0) + fabsf(on1 - t1)) + fabsf(on2 - t2)) + fabsf(on3 - t3);
    float notbc = (ib & ic) ? 0.0f : 1.0f;
    float c = ((5.0f * cb + 2.0f * ccls) + 2.0f * (-giou)) + 100.0f * notbc;
    c = c + fgadd;

    s_tile[qi * 65 + lane] = c;

    // row argmin over g (first-index tie-break == jnp.argmin)
    float bv = c; int bg = lane;
    for (int off = 32; off; off >>= 1) {
      float ov = __shfl_down(bv, off, 64); int og = __shfl_down(bg, off, 64);
      if (ov < bv || (ov == bv && og < bg)) { bv = ov; bg = og; }
    }
    if (lane == 0 && q < QQ) rowarg[b * QQ + q] = bg;
  }
  __syncthreads();

  // transposed store: consecutive threads -> consecutive q (coalesced)
  float* cb_out = cost + (size_t)b * GG * QQ;
  const int qi = t & 63;
  const int q = q0 + qi;
  if (q < QQ) {
    #pragma unroll
    for (int pass = 0; pass < 16; ++pass) {
      int g = (t >> 6) + pass * 4;
      cb_out[(size_t)g * QQ + q] = s_tile[qi * 65 + g];
    }
  }
}

// ---------------------------------------------------------------------------
// K2a: per (b, gt-column): dynamic_k (top-5 iou sum, trunc, >=1) and the
// k-smallest-cost query picks. One wave per column -> 2048 waves.
// ---------------------------------------------------------------------------
__global__ __launch_bounds__(256) void pick_kernel(
    const float* __restrict__ boxes, const float* __restrict__ gtb,
    const float* __restrict__ cost, int* __restrict__ picks) {
#pragma clang fp contract(off)
  const int gwave = blockIdx.x * 4 + (threadIdx.x >> 6);
  const int lane = threadIdx.x & 63;
  const int b = gwave >> 6, col = gwave & 63;

  const int gbase = (b * GG + col) * 4;
  const float gx1 = gtb[gbase + 0], gy1 = gtb[gbase + 1];
  const float gx2 = gtb[gbase + 2], gy2 = gtb[gbase + 3];
  const float ga = (gx2 - gx1) * (gy2 - gy1);

  float v[32];
  #pragma unroll
  for (int j = 0; j < 32; ++j) {
    int q = lane + (j << 6);
    if (q < QQ) {
      float4 bx = reinterpret_cast<const float4*>(boxes)[b * QQ + q];
      float areaa = (bx.z - bx.x) * (bx.w - bx.y);
      float ltx = fmaxf(bx.x, gx1), lty = fmaxf(bx.y, gy1);
      float rbx = fminf(bx.z, gx2), rby = fminf(bx.w, gy2);
      float iw = fmaxf(rbx - ltx, 0.0f), ih = fmaxf(rby - lty, 0.0f);
      float inter = iw * ih;
      v[j] = inter / ((areaa + ga) - inter);
    } else v[j] = -1.0f;
  }
  unsigned rm = 0u;
  float s = 0.0f;
  for (int pass = 0; pass < 5; ++pass) {
    float bv = -1e30f; int bq = 0x7fffffff;
    #pragma unroll
    for (int j = 0; j < 32; ++j) {
      int q = lane + (j << 6);
      if (q < QQ && !((rm >> j) & 1u) && v[j] > bv) { bv = v[j]; bq = q; }
    }
    for (int off = 32; off; off >>= 1) {
      float ov = __shfl_down(bv, off, 64); int oq = __shfl_down(bq, off, 64);
      if (ov > bv || (ov == bv && oq < bq)) { bv = ov; bq = oq; }
    }
    bv = __shfl(bv, 0, 64); bq = __shfl(bq, 0, 64);
    s += bv;                       // descending, left-assoc (top_k sum)
    if ((bq & 63) == lane) rm |= (1u << (bq >> 6));
  }
  int dynk = (int)s;               // trunc == astype(int32)
  if (dynk < 1) dynk = 1;

  const float* ccol = cost + (size_t)(b * GG + col) * QQ;
  #pragma unroll
  for (int j = 0; j < 32; ++j) {
    int q = lane + (j << 6);
    v[j] = (q < QQ) ? ccol[q] : 0.0f;
  }
  rm = 0u;
  int pk[5];
  for (int pass = 0; pass < 5; ++pass) {
    float bv = INFINITY; int bq = 0x7fffffff;
    #pragma unroll
    for (int j = 0; j < 32; ++j) {
      int q = lane + (j << 6);
      if (q < QQ && !((rm >> j) & 1u) && v[j] < bv) { bv = v[j]; bq = q; }
    }
    for (int off = 32; off; off >>= 1) {
      float ov = __shfl_down(bv, off, 64); int oq = __shfl_down(bq, off, 64);
      if (ov < bv || (ov == bv && oq < bq)) { bv = ov; bq = oq; }
    }
    bq = __shfl(bq, 0, 64);
    pk[pass] = bq;
    if ((bq & 63) == lane) rm |= (1u << (bq >> 6));
  }
  if (lane == 0) {
    int base = (b * GG + col) * 8;
    #pragma unroll
    for (int i = 0; i < 5; ++i) picks[base + i] = pk[i];
    picks[base + 5] = dynk;
  }
}

// ---------------------------------------------------------------------------
// K2b: the irreducibly serial per-batch loop. One block per b. Dedup is now a
// pure-LDS lookup (precomputed row argmin); global loads only for the rare
// unmatched-column argmins and the final masked (penalized) argmin.
// ---------------------------------------------------------------------------
__global__ __launch_bounds__(1024) void serial_kernel(
    const float* __restrict__ cost, const int* __restrict__ picks,
    const int* __restrict__ rowarg, uint2* __restrict__ bits,
    float* __restrict__ out_ids) {
#pragma clang fp contract(off)
  const int b = blockIdx.x;
  const int tid = threadIdx.x;
  const int w = tid >> 6, lane = tid & 63;

  __shared__ unsigned s_mlo[QQ], s_mhi[QQ];
  __shared__ unsigned short s_kpen[QQ];
  __shared__ short s_rarg[QQ];
  __shared__ int s_addq[GG];
  __shared__ unsigned s_rlo[16], s_rhi[16];
  __shared__ unsigned s_gmlo, s_gmhi;
  __shared__ int s_anyun;

  for (int q = tid; q < QQ; q += 1024) {
    s_mlo[q] = 0u; s_mhi[q] = 0u; s_kpen[q] = 0;
    s_rarg[q] = (short)rowarg[b * QQ + q];
  }
  __syncthreads();
  if (tid < GG) {
    int base = (b * GG + tid) * 8;
    int dynk = picks[base + 5];
    for (int i = 0; i < dynk; ++i) {
      int q = picks[base + i];
      if (tid < 32) atomicOr(&s_mlo[q], 1u << tid);
      else          atomicOr(&s_mhi[q], 1u << (tid - 32));
    }
  }
  __syncthreads();
  // initial dedup (over-rows -> one-hot at original-cost row argmin)
  for (int q = tid; q < QQ; q += 1024) {
    if (__popc(s_mlo[q]) + __popc(s_mhi[q]) > 1) {
      int bg = s_rarg[q];
      s_mlo[q] = (bg < 32) ? (1u << bg) : 0u;
      s_mhi[q] = (bg >= 32) ? (1u << (bg - 32)) : 0u;
    }
  }
  __syncthreads();

  const float* costb = cost + (size_t)b * GG * QQ;
  for (int iter = 0; iter < GG; ++iter) {
    unsigned lo = 0u, hi = 0u;
    for (int q = tid; q < QQ; q += 1024) { lo |= s_mlo[q]; hi |= s_mhi[q]; }
    for (int off = 32; off; off >>= 1) {
      lo |= __shfl_down(lo, off, 64); hi |= __shfl_down(hi, off, 64);
    }
    if (lane == 0) { s_rlo[w] = lo; s_rhi[w] = hi; }
    __syncthreads();
    if (tid == 0) {
      unsigned L = 0u, H = 0u;
      for (int i = 0; i < 16; ++i) { L |= s_rlo[i]; H |= s_rhi[i]; }
      s_gmlo = L; s_gmhi = H;
      s_anyun = (L != 0xffffffffu) || (H != 0xffffffffu);
    }
    __syncthreads();
    if (!s_anyun) break;
    const unsigned gmlo = s_gmlo, gmhi = s_gmhi;

    // +1e5 penalty bookkeeping for queries matched at iteration start
    for (int q = tid; q < QQ; q += 1024) if (s_mlo[q] | s_mhi[q]) s_kpen[q]++;

    // per unmatched gt: argmin over unmatched queries (penalized can't win)
    for (int col = w; col < GG; col += 16) {
      bool matched = (col < 32) ? ((gmlo >> col) & 1u) : ((gmhi >> (col - 32)) & 1u);
      if (matched) continue;
      const float* ccol = costb + (size_t)col * QQ;
      float bv = INFINITY; int bq = 0x7fffffff;
      for (int q = lane; q < QQ; q += 64) {
        if ((s_mlo[q] | s_mhi[q]) == 0u) {
          float cv = ccol[q];
          if (cv < bv) { bv = cv; bq = q; }
        }
      }
      for (int off = 32; off; off >>= 1) {
        float ov = __shfl_down(bv, off, 64); int oq = __shfl_down(bq, off, 64);
        if (ov < bv || (ov == bv && oq < bq)) { bv = ov; bq = oq; }
      }
      if (lane == 0) s_addq[col] = bq;
    }
    __syncthreads();
    if (tid < GG) {
      bool matched = (tid < 32) ? ((gmlo >> tid) & 1u) : ((gmhi >> (tid - 32)) & 1u);
      if (!matched) {
        int q = s_addq[tid];
        if (tid < 32) atomicOr(&s_mlo[q], 1u << tid);
        else          atomicOr(&s_mhi[q], 1u << (tid - 32));
      }
    }
    __syncthreads();
    // dedup: over-rows are freshly added (unpenalized) -> original row argmin
    for (int q = tid; q < QQ; q += 1024) {
      if (__popc(s_mlo[q]) + __popc(s_mhi[q]) > 1) {
        int bg = s_rarg[q];
        s_mlo[q] = (bg < 32) ? (1u << bg) : 0u;
        s_mhi[q] = (bg >= 32) ? (1u << (bg - 32)) : 0u;
      }
    }
    __syncthreads();
  }

  // matched_query_id: masked argmin with the exact FP penalty chain replayed
  for (int col = w; col < GG; col += 16) {
    const float* ccol = costb + (size_t)col * QQ;
    float bv = INFINITY; int bq = 0x7fffffff;
    for (int q = lane; q < QQ; q += 64) {
      unsigned m = (col < 32) ? s_mlo[q] : s_mhi[q];
      if ((m >> (col & 31)) & 1u) {
        float cv = ccol[q];
        int k = s_kpen[q];
        for (int tt = 0; tt < k; ++tt) cv += 1e5f;
        if (cv < bv) { bv = cv; bq = q; }
      }
    }
    for (int off = 32; off; off >>= 1) {
      float ov = __shfl_down(bv, off, 64); int oq = __shfl_down(bq, off, 64);
      if (ov < bv || (ov == bv && oq < bq)) { bv = ov; bq = oq; }
    }
    if (lane == 0) out_ids[b * GG + col] = (float)((bq == 0x7fffffff) ? 0 : bq);
  }

  for (int q = tid; q < QQ; q += 1024) bits[b * QQ + q] = make_uint2(s_mlo[q], s_mhi[q]);
}

// ---------------------------------------------------------------------------
// K2c: expand bit masks -> [B,Q,G] float matching matrix, grid-wide, float4.
// ---------------------------------------------------------------------------
__global__ __launch_bounds__(256) void expand_kernel(
    const uint2* __restrict__ bits, float* __restrict__ out_match) {
  int idx = blockIdx.x * 256 + threadIdx.x;      // [0, B*Q*16)
  if (idx >= BB * QQ * 16) return;
  int g4 = idx & 15;
  int bq = idx >> 4;
  uint2 m = bits[bq];
  unsigned mm = (g4 < 8) ? m.x : m.y;
  int sh = (g4 * 4) & 31;
  float4 o;
  o.x = (float)((mm >> (sh + 0)) & 1u);
  o.y = (float)((mm >> (sh + 1)) & 1u);
  o.z = (float)((mm >> (sh + 2)) & 1u);
  o.w = (float)((mm >> (sh + 3)) & 1u);
  reinterpret_cast<float4*>(out_match)[idx] = o;
}

extern "C" void kernel_launch(void* const* d_in, const int* in_sizes, int n_in,
                              void* d_out, int out_size, void* d_ws, size_t ws_size,
                              hipStream_t stream) {
  const float* logits = (const float*)d_in[0];
  const float* boxes  = (const float*)d_in[1];
  const int*   gtc    = (const int*)d_in[2];
  const float* gtbx   = (const float*)d_in[3];
  const float* szout  = (const float*)d_in[4];
  const float* sztgt  = (const float*)d_in[5];
  float* out = (float*)d_out;

  const size_t costN   = (size_t)BB * GG * QQ;   // 4,096,000 floats
  const size_t rowargN = (size_t)BB * QQ;        // ints
  const size_t picksN  = (size_t)BB * GG * 8;    // ints
  const size_t bitsN   = (size_t)BB * QQ;        // uint2

  char* wsb = (char*)d_ws;
  float* cost; int* rowarg; int* picks; uint2* bits;
  const size_t extras = rowargN * 4 + picksN * 4 + bitsN * 8;
  if (ws_size >= costN * 4 + extras) {
    cost   = (float*)wsb;
    rowarg = (int*)(wsb + costN * 4);
    picks  = rowarg + rowargN;
    bits   = (uint2*)(picks + picksN);
  } else {
    // stage cost in the matching-output region (expand_kernel overwrites it
    // last); small scratch arrays in ws.
    cost   = out;
    rowarg = (int*)wsb;
    picks  = rowarg + rowargN;
    bits   = (uint2*)(picks + picksN);
  }
  float* out_ids = out + costN;                  // matching is exactly B*Q*G floats

  hipLaunchKernelGGL(cost_kernel, dim3(32, BB), dim3(256), 0, stream,
                     logits, boxes, gtc, gtbx, szout, sztgt, cost, rowarg);
  hipLaunchKernelGGL(pick_kernel, dim3(BB * GG / 4), dim3(256), 0, stream,
                     boxes, gtbx, cost, picks);
  hipLaunchKernelGGL(serial_kernel, dim3(BB), dim3(1024), 0, stream,
                     cost, picks, rowarg, bits, out_ids);
  hipLaunchKernelGGL(expand_kernel, dim3((BB * QQ * 16) / 256), dim3(256), 0, stream,
                     bits, out);
}

// Round 3
// 151.468 us; speedup vs baseline: 1.8609x; 1.0942x over previous
//
#include <hip/hip_runtime.h>
#include <cmath>

#pragma clang fp contract(off)

#define BB 32
#define QQ 2000
#define GG 64
#define CCH 80
#define TOPC 16

// ---------------------------------------------------------------------------
// K1: cost matrix in [b][g][q] layout + per-query row argmin.
// Orientation: lane = gt index, each wave processes 16 queries serially.
// ---------------------------------------------------------------------------
__global__ __launch_bounds__(256) void cost_kernel(
    const float* __restrict__ logits, const float* __restrict__ boxes,
    const int* __restrict__ gtc, const float* __restrict__ gtb,
    const float* __restrict__ szout, const float* __restrict__ sztgt,
    float* __restrict__ cost, int* __restrict__ rowarg) {
#pragma clang fp contract(off)
  const int b = blockIdx.y;
  const int q0 = blockIdx.x * 64;
  const int t = threadIdx.x;
  const int w = t >> 6, lane = t & 63;

  __shared__ float4 s_qb[64];
  __shared__ float s_tile[64 * 65];

  const int gbase = (b * GG + lane) * 4;
  const float g0 = gtb[gbase + 0], g1 = gtb[gbase + 1];
  const float g2 = gtb[gbase + 2], g3 = gtb[gbase + 3];
  const float t0 = g0 / sztgt[gbase + 0], t1 = g1 / sztgt[gbase + 1];
  const float t2 = g2 / sztgt[gbase + 2], t3 = g3 / sztgt[gbase + 3];
  const float garea = (g2 - g0) * (g3 - g1);
  const float gcx = (g0 + g2) * 0.5f, gcy = (g1 + g3) * 0.5f;
  const float gw = g2 - g0, gh = g3 - g1;
  const float cxlo = gcx - 2.5f * gw, cxhi = gcx + 2.5f * gw;
  const float cylo = gcy - 2.5f * gh, cyhi = gcy + 2.5f * gh;
  const int cls = gtc[b * GG + lane];
  const float so0 = szout[b * 4 + 0], so1 = szout[b * 4 + 1];
  const float so2 = szout[b * 4 + 2], so3 = szout[b * 4 + 3];

  if (t < 64) {
    int q = q0 + t;
    s_qb[t] = (q < QQ) ? reinterpret_cast<const float4*>(boxes)[b * QQ + q]
                       : make_float4(0.f, 0.f, 1.f, 1.f);
  }
  __syncthreads();

  const float* lbase = logits + (size_t)b * QQ * CCH;
  for (int i = 0; i < 16; ++i) {
    const int qi = w * 16 + i;
    const int q = q0 + qi;
    float4 bx = s_qb[qi];
    float x1 = bx.x, y1 = bx.y, x2 = bx.z, y2 = bx.w;
    float on0 = x1 / so0, on1 = y1 / so1, on2 = x2 / so2, on3 = y2 / so3;
    float cx = (x1 + x2) * 0.5f, cy = (y1 + y2) * 0.5f;
    float areaa = (x2 - x1) * (y2 - y1);

    bool ib = (cx > g0) & (cx < g2) & (cy > g1) & (cy < g3);
    bool ic = (cx > cxlo) & (cx < cxhi) & (cy > cylo) & (cy < cyhi);
    bool fg = (__ballot(ib) != 0ull) || (__ballot(ic) != 0ull);
    float fgadd = fg ? 0.0f : 1e4f;

    float ltx = fmaxf(x1, g0), lty = fmaxf(y1, g1);
    float rbx = fminf(x2, g2), rby = fminf(y2, g3);
    float iw = fmaxf(rbx - ltx, 0.0f), ih = fmaxf(rby - lty, 0.0f);
    float inter = iw * ih;
    float uni = (areaa + garea) - inter;
    float iou = inter / uni;
    float ex1 = fminf(x1, g0), ey1 = fminf(y1, g1);
    float ex2 = fmaxf(x2, g2), ey2 = fmaxf(y2, g3);
    float ew = fmaxf(ex2 - ex1, 0.0f), eh = fmaxf(ey2 - ey1, 0.0f);
    float areac = ew * eh;
    float giou = iou - (areac - uni) / areac;

    float p = (q < QQ) ? lbase[(size_t)q * CCH + cls] : 0.5f;
    float negc = (0.75f * (p * p)) * (-logf((1.0f - p) + 1e-8f));
    float posc = (0.25f * ((1.0f - p) * (1.0f - p))) * (-logf(p + 1e-8f));
    float ccls = posc - negc;

    float cb = ((fabsf(on0 - t0) + fabsf(on1 - t1)) + fabsf(on2 - t2)) + fabsf(on3 - t3);
    float notbc = (ib & ic) ? 0.0f : 1.0f;
    float c = ((5.0f * cb + 2.0f * ccls) + 2.0f * (-giou)) + 100.0f * notbc;
    c = c + fgadd;

    s_tile[qi * 65 + lane] = c;

    float bv = c; int bg = lane;
    for (int off = 32; off; off >>= 1) {
      float ov = __shfl_down(bv, off, 64); int og = __shfl_down(bg, off, 64);
      if (ov < bv || (ov == bv && og < bg)) { bv = ov; bg = og; }
    }
    if (lane == 0 && q < QQ) rowarg[b * QQ + q] = bg;
  }
  __syncthreads();

  float* cb_out = cost + (size_t)b * GG * QQ;
  const int qi = t & 63;
  const int q = q0 + qi;
  if (q < QQ) {
    #pragma unroll
    for (int pass = 0; pass < 16; ++pass) {
      int g = (t >> 6) + pass * 4;
      cb_out[(size_t)g * QQ + q] = s_tile[qi * 65 + g];
    }
  }
}

// ---------------------------------------------------------------------------
// K2a: per (b,col): dynamic_k (top-5 iou sum) + the column's TOPC smallest-
// cost queries in exact (value, index) ascending order. One wave per column.
// The first dynk entries ARE the initial matching picks.
// ---------------------------------------------------------------------------
__global__ __launch_bounds__(256) void pick_kernel(
    const float* __restrict__ boxes, const float* __restrict__ gtb,
    const float* __restrict__ cost, short* __restrict__ lists,
    int* __restrict__ dynks) {
#pragma clang fp contract(off)
  const int gwave = blockIdx.x * 4 + (threadIdx.x >> 6);
  const int lane = threadIdx.x & 63;
  const int b = gwave >> 6, col = gwave & 63;

  const int gbase = (b * GG + col) * 4;
  const float gx1 = gtb[gbase + 0], gy1 = gtb[gbase + 1];
  const float gx2 = gtb[gbase + 2], gy2 = gtb[gbase + 3];
  const float ga = (gx2 - gx1) * (gy2 - gy1);

  float v[32];
  #pragma unroll
  for (int j = 0; j < 32; ++j) {
    int q = lane + (j << 6);
    if (q < QQ) {
      float4 bx = reinterpret_cast<const float4*>(boxes)[b * QQ + q];
      float areaa = (bx.z - bx.x) * (bx.w - bx.y);
      float ltx = fmaxf(bx.x, gx1), lty = fmaxf(bx.y, gy1);
      float rbx = fminf(bx.z, gx2), rby = fminf(bx.w, gy2);
      float iw = fmaxf(rbx - ltx, 0.0f), ih = fmaxf(rby - lty, 0.0f);
      float inter = iw * ih;
      v[j] = inter / ((areaa + ga) - inter);
    } else v[j] = -1.0f;
  }
  unsigned rm = 0u;
  float s = 0.0f;
  for (int pass = 0; pass < 5; ++pass) {
    float bv = -1e30f; int bq = 0x7fffffff;
    #pragma unroll
    for (int j = 0; j < 32; ++j) {
      int q = lane + (j << 6);
      if (q < QQ && !((rm >> j) & 1u) && v[j] > bv) { bv = v[j]; bq = q; }
    }
    for (int off = 32; off; off >>= 1) {
      float ov = __shfl_down(bv, off, 64); int oq = __shfl_down(bq, off, 64);
      if (ov > bv || (ov == bv && oq < bq)) { bv = ov; bq = oq; }
    }
    bv = __shfl(bv, 0, 64); bq = __shfl(bq, 0, 64);
    s += bv;                       // descending, left-assoc (top_k sum)
    if ((bq & 63) == lane) rm |= (1u << (bq >> 6));
  }
  int dynk = (int)s;               // trunc == astype(int32)
  if (dynk < 1) dynk = 1;
  if (lane == 0) dynks[b * GG + col] = dynk;

  const float* ccol = cost + (size_t)(b * GG + col) * QQ;
  #pragma unroll
  for (int j = 0; j < 32; ++j) {
    int q = lane + (j << 6);
    v[j] = (q < QQ) ? ccol[q] : 0.0f;
  }
  rm = 0u;
  for (int pass = 0; pass < TOPC; ++pass) {
    float bv = INFINITY; int bq = 0x7fffffff;
    #pragma unroll
    for (int j = 0; j < 32; ++j) {
      int q = lane + (j << 6);
      if (q < QQ && !((rm >> j) & 1u) && v[j] < bv) { bv = v[j]; bq = q; }
    }
    for (int off = 32; off; off >>= 1) {
      float ov = __shfl_down(bv, off, 64); int oq = __shfl_down(bq, off, 64);
      if (ov < bv || (ov == bv && oq < bq)) { bv = ov; bq = oq; }
    }
    bq = __shfl(bq, 0, 64);
    if (lane == 0) lists[(b * GG + col) * TOPC + pass] = (short)bq;
    if ((bq & 63) == lane) rm |= (1u << (bq >> 6));
  }
}

// ---------------------------------------------------------------------------
// K2b: serial per-batch loop — pure LDS. 256 threads (4 waves) per batch.
// Incremental per-gt match counts; added-list dedup; first-iter bookkeeping
// (kpen[q] = T - first[q] since matched queries never unmatch); candidate-
// list walk replaces column scans (exact: penalized rows can't win argmin
// while unmatched rows exist; dedup row-argmin invariant to uniform row
// penalty).
// ---------------------------------------------------------------------------
__global__ __launch_bounds__(256) void serial_kernel(
    const float* __restrict__ cost, const short* __restrict__ lists,
    const int* __restrict__ dynks, const int* __restrict__ rowarg,
    uint2* __restrict__ bits, float* __restrict__ out_ids) {
#pragma clang fp contract(off)
  const int b = blockIdx.x;
  const int tid = threadIdx.x;
  const int w = tid >> 6, lane = tid & 63;

  __shared__ unsigned s_mlo[QQ], s_mhi[QQ];
  __shared__ int s_first[QQ];
  __shared__ int s_pushed[QQ];
  __shared__ short s_rarg[QQ];
  __shared__ short s_list[GG * TOPC];
  __shared__ int s_cnt[GG];
  __shared__ short s_chosen[GG];
  __shared__ unsigned long long s_pack[GG];
  __shared__ int s_added[128];
  __shared__ unsigned s_gmlo, s_gmhi;
  __shared__ int s_anyun, s_nadd;

  for (int q = tid; q < QQ; q += 256) {
    s_mlo[q] = 0u; s_mhi[q] = 0u; s_first[q] = -1; s_pushed[q] = -1;
    s_rarg[q] = (short)rowarg[b * QQ + q];
  }
  for (int i = tid; i < GG * TOPC; i += 256) s_list[i] = lists[b * GG * TOPC + i];
  if (tid < GG) s_cnt[tid] = 0;
  __syncthreads();

  // initial matching: first dynk list entries per column
  if (tid < GG) {
    int dynk = dynks[b * GG + tid];
    s_cnt[tid] = dynk;
    for (int i = 0; i < dynk; ++i) {
      int q = s_list[tid * TOPC + i];
      if (tid < 32) atomicOr(&s_mlo[q], 1u << tid);
      else          atomicOr(&s_mhi[q], 1u << (tid - 32));
      s_first[q] = 0;                    // benign same-value race
    }
  }
  __syncthreads();

  // initial dedup: strip over-queries to one-hot at row argmin
  for (int q = tid; q < QQ; q += 256) {
    unsigned lo = s_mlo[q], hi = s_mhi[q];
    if (__popc(lo) + __popc(hi) > 1) {
      int bg = s_rarg[q];
      unsigned tl = lo, th = hi;
      while (tl) { int g = __ffs(tl) - 1; tl &= tl - 1; if (g != bg) atomicSub(&s_cnt[g], 1); }
      while (th) { int g = __ffs(th) + 31; th &= th - 1; if (g != bg) atomicSub(&s_cnt[g], 1); }
      bool had = (bg < 32) ? ((lo >> bg) & 1u) : ((hi >> (bg - 32)) & 1u);
      if (!had) atomicAdd(&s_cnt[bg], 1);
      s_mlo[q] = (bg < 32) ? (1u << bg) : 0u;
      s_mhi[q] = (bg >= 32) ? (1u << (bg - 32)) : 0u;
    }
  }

  const float* costb = cost + (size_t)b * GG * QQ;
  int T = 0;
  for (int iter = 0; iter < GG; ++iter) {
    __syncthreads();
    if (tid < 64) {
      unsigned long long bal = __ballot(s_cnt[tid] > 0);
      if (tid == 0) {
        s_gmlo = (unsigned)bal; s_gmhi = (unsigned)(bal >> 32);
        s_anyun = ((~bal) != 0ull); s_nadd = 0;
      }
    }
    __syncthreads();
    if (!s_anyun) break;
    T++;
    const unsigned gmlo = s_gmlo, gmhi = s_gmhi;

    // phase b: per unmatched col, pick argmin over unmatched queries
    for (int col = w; col < GG; col += 4) {
      bool matched = (col < 32) ? ((gmlo >> col) & 1u) : ((gmhi >> (col - 32)) & 1u);
      if (matched) continue;
      int cq = s_list[col * TOPC + (lane & (TOPC - 1))];
      bool cand_un = (lane < TOPC) && ((s_mlo[cq] | s_mhi[cq]) == 0u);
      unsigned long long bal = __ballot(cand_un);
      int q;
      if (bal) {
        q = s_list[col * TOPC + (__ffsll(bal) - 1)];
      } else {
        // fallback 1: full masked scan (argmin over unmatched)
        const float* ccol = costb + (size_t)col * QQ;
        float bv = INFINITY; int bq = 0x7fffffff;
        for (int q2 = lane; q2 < QQ; q2 += 64) {
          if ((s_mlo[q2] | s_mhi[q2]) == 0u) {
            float cv = ccol[q2];
            if (cv < bv) { bv = cv; bq = q2; }
          }
        }
        for (int off = 32; off; off >>= 1) {
          float ov = __shfl_down(bv, off, 64); int oq = __shfl_down(bq, off, 64);
          if (ov < bv || (ov == bv && oq < bq)) { bv = ov; bq = oq; }
        }
        bq = __shfl(bq, 0, 64);
        if (bq == 0x7fffffff) {
          // fallback 2 (unreachable in practice): all queries matched ->
          // argmin over penalized values with exact replay
          bv = INFINITY; bq = 0x7fffffff;
          for (int q2 = lane; q2 < QQ; q2 += 64) {
            float cv = ccol[q2];
            int k = (s_first[q2] >= 0) ? (iter + 1 - s_first[q2]) : 0;
            for (int tt = 0; tt < k; ++tt) cv += 1e5f;
            if (cv < bv) { bv = cv; bq = q2; }
          }
          for (int off = 32; off; off >>= 1) {
            float ov = __shfl_down(bv, off, 64); int oq = __shfl_down(bq, off, 64);
            if (ov < bv || (ov == bv && oq < bq)) { bv = ov; bq = oq; }
          }
          bq = __shfl(bq, 0, 64);
        }
        q = bq;
      }
      if (lane == 0) s_chosen[col] = (short)q;
    }
    __syncthreads();

    // phase d: apply adds
    if (tid < 64) {
      bool matched = (tid < 32) ? ((gmlo >> tid) & 1u) : ((gmhi >> (tid - 32)) & 1u);
      if (!matched) {
        int q = s_chosen[tid];
        if (tid < 32) atomicOr(&s_mlo[q], 1u << tid);
        else          atomicOr(&s_mhi[q], 1u << (tid - 32));
        atomicAdd(&s_cnt[tid], 1);
        if (s_first[q] == -1) s_first[q] = iter + 1;   // same-value race ok
        if (atomicExch(&s_pushed[q], iter) != iter) {  // dedupe pushes
          int slot = atomicAdd(&s_nadd, 1);
          s_added[slot] = q;
        }
      }
    }
    __syncthreads();

    // phase e: dedup just-added queries
    if (tid < s_nadd) {
      int q = s_added[tid];
      unsigned lo = s_mlo[q], hi = s_mhi[q];
      if (__popc(lo) + __popc(hi) > 1) {
        int bg = s_rarg[q];
        unsigned tl = lo, th = hi;
        while (tl) { int g = __ffs(tl) - 1; tl &= tl - 1; if (g != bg) atomicSub(&s_cnt[g], 1); }
        while (th) { int g = __ffs(th) + 31; th &= th - 1; if (g != bg) atomicSub(&s_cnt[g], 1); }
        bool had = (bg < 32) ? ((lo >> bg) & 1u) : ((hi >> (bg - 32)) & 1u);
        if (!had) atomicAdd(&s_cnt[bg], 1);
        s_mlo[q] = (bg < 32) ? (1u << bg) : 0u;
        s_mhi[q] = (bg >= 32) ? (1u << (bg - 32)) : 0u;
      }
    }
  }

  // final ids: scatter-argmin over matched queries with exact penalty replay
  if (tid < GG) s_pack[tid] = 0xFFFFFFFFFFFFFFFFull;
  __syncthreads();
  for (int q = tid; q < QQ; q += 256) {
    unsigned lo = s_mlo[q], hi = s_mhi[q];
    if (lo | hi) {
      int g = lo ? (__ffs(lo) - 1) : (__ffs(hi) + 31);
      float cv = costb[(size_t)g * QQ + q];
      int k = T - s_first[q];
      for (int tt = 0; tt < k; ++tt) cv += 1e5f;
      unsigned ub = __float_as_uint(cv);
      ub = (ub & 0x80000000u) ? ~ub : (ub | 0x80000000u);
      unsigned long long pk = ((unsigned long long)ub << 16) | (unsigned)q;
      atomicMin(&s_pack[g], pk);
    }
  }
  __syncthreads();
  if (tid < GG) {
    unsigned long long pk = s_pack[tid];
    out_ids[b * GG + tid] =
        (pk == 0xFFFFFFFFFFFFFFFFull) ? 0.0f : (float)(pk & 0xFFFFull);
  }
  for (int q = tid; q < QQ; q += 256) bits[b * QQ + q] = make_uint2(s_mlo[q], s_mhi[q]);
}

// ---------------------------------------------------------------------------
// K2c: expand bit masks -> [B,Q,G] float matching matrix, grid-wide, float4.
// ---------------------------------------------------------------------------
__global__ __launch_bounds__(256) void expand_kernel(
    const uint2* __restrict__ bits, float* __restrict__ out_match) {
  int idx = blockIdx.x * 256 + threadIdx.x;      // [0, B*Q*16)
  if (idx >= BB * QQ * 16) return;
  int g4 = idx & 15;
  int bq = idx >> 4;
  uint2 m = bits[bq];
  unsigned mm = (g4 < 8) ? m.x : m.y;
  int sh = (g4 * 4) & 31;
  float4 o;
  o.x = (float)((mm >> (sh + 0)) & 1u);
  o.y = (float)((mm >> (sh + 1)) & 1u);
  o.z = (float)((mm >> (sh + 2)) & 1u);
  o.w = (float)((mm >> (sh + 3)) & 1u);
  reinterpret_cast<float4*>(out_match)[idx] = o;
}

extern "C" void kernel_launch(void* const* d_in, const int* in_sizes, int n_in,
                              void* d_out, int out_size, void* d_ws, size_t ws_size,
                              hipStream_t stream) {
  const float* logits = (const float*)d_in[0];
  const float* boxes  = (const float*)d_in[1];
  const int*   gtc    = (const int*)d_in[2];
  const float* gtbx   = (const float*)d_in[3];
  const float* szout  = (const float*)d_in[4];
  const float* sztgt  = (const float*)d_in[5];
  float* out = (float*)d_out;

  const size_t costN   = (size_t)BB * GG * QQ;     // floats
  const size_t rowargN = (size_t)BB * QQ;          // ints
  const size_t listsN  = (size_t)BB * GG * TOPC;   // shorts
  const size_t dynksN  = (size_t)BB * GG;          // ints
  const size_t bitsN   = (size_t)BB * QQ;          // uint2

  char* wsb = (char*)d_ws;
  const size_t extras = rowargN * 4 + listsN * 2 + dynksN * 4 + bitsN * 8;
  float* cost; char* p;
  if (ws_size >= costN * 4 + extras) {
    cost = (float*)wsb;
    p = wsb + costN * 4;
  } else {
    // stage cost in the matching-output region (expand overwrites it last)
    cost = out;
    p = wsb;
  }
  int*   rowarg = (int*)p;            p += rowargN * 4;
  short* lists  = (short*)p;          p += listsN * 2;
  int*   dynks  = (int*)p;            p += dynksN * 4;
  uint2* bits   = (uint2*)p;

  float* out_ids = out + costN;       // matching is exactly B*Q*G floats

  hipLaunchKernelGGL(cost_kernel, dim3(32, BB), dim3(256), 0, stream,
                     logits, boxes, gtc, gtbx, szout, sztgt, cost, rowarg);
  hipLaunchKernelGGL(pick_kernel, dim3(BB * GG / 4), dim3(256), 0, stream,
                     boxes, gtbx, cost, lists, dynks);
  hipLaunchKernelGGL(serial_kernel, dim3(BB), dim3(256), 0, stream,
                     cost, lists, dynks, rowarg, bits, out_ids);
  hipLaunchKernelGGL(expand_kernel, dim3((BB * QQ * 16) / 256), dim3(256), 0, stream,
                     bits, out);
}

// Round 4
// 147.547 us; speedup vs baseline: 1.9104x; 1.0266x over previous
//
#include <hip/hip_runtime.h>
#include <cmath>

#pragma clang fp contract(off)

#define BB 32
#define QQ 2000
#define GG 64
#define CCH 80
#define TOPC 16

// ---------------------------------------------------------------------------
// K1: cost matrix in [b][g][q] layout + per-query row argmin + zero-fill of
// the matching output region (serial_kernel scatters the ones later).
// Orientation: lane = gt index, each wave processes 16 queries serially.
// ---------------------------------------------------------------------------
__global__ __launch_bounds__(256) void cost_kernel(
    const float* __restrict__ logits, const float* __restrict__ boxes,
    const int* __restrict__ gtc, const float* __restrict__ gtb,
    const float* __restrict__ szout, const float* __restrict__ sztgt,
    float* __restrict__ cost, int* __restrict__ rowarg,
    float* __restrict__ out_match) {
#pragma clang fp contract(off)
  const int b = blockIdx.y;
  const int q0 = blockIdx.x * 64;
  const int t = threadIdx.x;
  const int w = t >> 6, lane = t & 63;

  __shared__ float4 s_qb[64];
  __shared__ float s_tile[64 * 65];

  const int gbase = (b * GG + lane) * 4;
  const float g0 = gtb[gbase + 0], g1 = gtb[gbase + 1];
  const float g2 = gtb[gbase + 2], g3 = gtb[gbase + 3];
  const float t0 = g0 / sztgt[gbase + 0], t1 = g1 / sztgt[gbase + 1];
  const float t2 = g2 / sztgt[gbase + 2], t3 = g3 / sztgt[gbase + 3];
  const float garea = (g2 - g0) * (g3 - g1);
  const float gcx = (g0 + g2) * 0.5f, gcy = (g1 + g3) * 0.5f;
  const float gw = g2 - g0, gh = g3 - g1;
  const float cxlo = gcx - 2.5f * gw, cxhi = gcx + 2.5f * gw;
  const float cylo = gcy - 2.5f * gh, cyhi = gcy + 2.5f * gh;
  const int cls = gtc[b * GG + lane];
  const float so0 = szout[b * 4 + 0], so1 = szout[b * 4 + 1];
  const float so2 = szout[b * 4 + 2], so3 = szout[b * 4 + 3];

  if (t < 64) {
    int q = q0 + t;
    s_qb[t] = (q < QQ) ? reinterpret_cast<const float4*>(boxes)[b * QQ + q]
                       : make_float4(0.f, 0.f, 1.f, 1.f);
  }
  __syncthreads();

  const float* lbase = logits + (size_t)b * QQ * CCH;
  for (int i = 0; i < 16; ++i) {
    const int qi = w * 16 + i;
    const int q = q0 + qi;
    float4 bx = s_qb[qi];
    float x1 = bx.x, y1 = bx.y, x2 = bx.z, y2 = bx.w;
    float on0 = x1 / so0, on1 = y1 / so1, on2 = x2 / so2, on3 = y2 / so3;
    float cx = (x1 + x2) * 0.5f, cy = (y1 + y2) * 0.5f;
    float areaa = (x2 - x1) * (y2 - y1);

    bool ib = (cx > g0) & (cx < g2) & (cy > g1) & (cy < g3);
    bool ic = (cx > cxlo) & (cx < cxhi) & (cy > cylo) & (cy < cyhi);
    bool fg = (__ballot(ib) != 0ull) || (__ballot(ic) != 0ull);
    float fgadd = fg ? 0.0f : 1e4f;

    float ltx = fmaxf(x1, g0), lty = fmaxf(y1, g1);
    float rbx = fminf(x2, g2), rby = fminf(y2, g3);
    float iw = fmaxf(rbx - ltx, 0.0f), ih = fmaxf(rby - lty, 0.0f);
    float inter = iw * ih;
    float uni = (areaa + garea) - inter;
    float iou = inter / uni;
    float ex1 = fminf(x1, g0), ey1 = fminf(y1, g1);
    float ex2 = fmaxf(x2, g2), ey2 = fmaxf(y2, g3);
    float ew = fmaxf(ex2 - ex1, 0.0f), eh = fmaxf(ey2 - ey1, 0.0f);
    float areac = ew * eh;
    float giou = iou - (areac - uni) / areac;

    float p = (q < QQ) ? lbase[(size_t)q * CCH + cls] : 0.5f;
    float negc = (0.75f * (p * p)) * (-logf((1.0f - p) + 1e-8f));
    float posc = (0.25f * ((1.0f - p) * (1.0f - p))) * (-logf(p + 1e-8f));
    float ccls = posc - negc;

    float cb = ((fabsf(on0 - t0) + fabsf(on1 - t1)) + fabsf(on2 - t2)) + fabsf(on3 - t3);
    float notbc = (ib & ic) ? 0.0f : 1.0f;
    float c = ((5.0f * cb + 2.0f * ccls) + 2.0f * (-giou)) + 100.0f * notbc;
    c = c + fgadd;

    s_tile[qi * 65 + lane] = c;

    float bv = c; int bg = lane;
    for (int off = 32; off; off >>= 1) {
      float ov = __shfl_down(bv, off, 64); int og = __shfl_down(bg, off, 64);
      if (ov < bv || (ov == bv && og < bg)) { bv = ov; bg = og; }
    }
    if (lane == 0 && q < QQ) rowarg[b * QQ + q] = bg;
  }
  __syncthreads();

  float* cb_out = cost + (size_t)b * GG * QQ;
  const int qi = t & 63;
  const int q = q0 + qi;
  if (q < QQ) {
    #pragma unroll
    for (int pass = 0; pass < 16; ++pass) {
      int g = (t >> 6) + pass * 4;
      cb_out[(size_t)g * QQ + q] = s_tile[qi * 65 + g];
    }
  }

  // zero-fill this block's slice of the matching output [b][q0..q0+63][:]
  int nq = QQ - q0; if (nq > 64) nq = 64;
  if (nq > 0) {
    float4* zb = reinterpret_cast<float4*>(out_match + ((size_t)b * QQ + q0) * GG);
    int n4 = nq * GG / 4;
    float4 z = make_float4(0.f, 0.f, 0.f, 0.f);
    for (int i = t; i < n4; i += 256) zb[i] = z;
  }
}

// ---------------------------------------------------------------------------
// K2a: per (b,col): dynamic_k (top-5 iou sum) + the column's TOPC smallest-
// cost queries in exact (value, index) ascending order. One wave per column.
// The first dynk entries ARE the initial matching picks.
// ---------------------------------------------------------------------------
__global__ __launch_bounds__(256) void pick_kernel(
    const float* __restrict__ boxes, const float* __restrict__ gtb,
    const float* __restrict__ cost, short* __restrict__ lists,
    int* __restrict__ dynks) {
#pragma clang fp contract(off)
  const int gwave = blockIdx.x * 4 + (threadIdx.x >> 6);
  const int lane = threadIdx.x & 63;
  const int b = gwave >> 6, col = gwave & 63;

  const int gbase = (b * GG + col) * 4;
  const float gx1 = gtb[gbase + 0], gy1 = gtb[gbase + 1];
  const float gx2 = gtb[gbase + 2], gy2 = gtb[gbase + 3];
  const float ga = (gx2 - gx1) * (gy2 - gy1);

  float v[32];
  #pragma unroll
  for (int j = 0; j < 32; ++j) {
    int q = lane + (j << 6);
    if (q < QQ) {
      float4 bx = reinterpret_cast<const float4*>(boxes)[b * QQ + q];
      float areaa = (bx.z - bx.x) * (bx.w - bx.y);
      float ltx = fmaxf(bx.x, gx1), lty = fmaxf(bx.y, gy1);
      float rbx = fminf(bx.z, gx2), rby = fminf(bx.w, gy2);
      float iw = fmaxf(rbx - ltx, 0.0f), ih = fmaxf(rby - lty, 0.0f);
      float inter = iw * ih;
      v[j] = inter / ((areaa + ga) - inter);
    } else v[j] = -1.0f;
  }
  unsigned rm = 0u;
  float s = 0.0f;
  for (int pass = 0; pass < 5; ++pass) {
    float bv = -1e30f; int bq = 0x7fffffff;
    #pragma unroll
    for (int j = 0; j < 32; ++j) {
      int q = lane + (j << 6);
      if (q < QQ && !((rm >> j) & 1u) && v[j] > bv) { bv = v[j]; bq = q; }
    }
    for (int off = 32; off; off >>= 1) {
      float ov = __shfl_down(bv, off, 64); int oq = __shfl_down(bq, off, 64);
      if (ov > bv || (ov == bv && oq < bq)) { bv = ov; bq = oq; }
    }
    bv = __shfl(bv, 0, 64); bq = __shfl(bq, 0, 64);
    s += bv;                       // descending, left-assoc (top_k sum)
    if ((bq & 63) == lane) rm |= (1u << (bq >> 6));
  }
  int dynk = (int)s;               // trunc == astype(int32)
  if (dynk < 1) dynk = 1;
  if (lane == 0) dynks[b * GG + col] = dynk;

  const float* ccol = cost + (size_t)(b * GG + col) * QQ;
  #pragma unroll
  for (int j = 0; j < 32; ++j) {
    int q = lane + (j << 6);
    v[j] = (q < QQ) ? ccol[q] : 0.0f;
  }
  rm = 0u;
  for (int pass = 0; pass < TOPC; ++pass) {
    float bv = INFINITY; int bq = 0x7fffffff;
    #pragma unroll
    for (int j = 0; j < 32; ++j) {
      int q = lane + (j << 6);
      if (q < QQ && !((rm >> j) & 1u) && v[j] < bv) { bv = v[j]; bq = q; }
    }
    for (int off = 32; off; off >>= 1) {
      float ov = __shfl_down(bv, off, 64); int oq = __shfl_down(bq, off, 64);
      if (ov < bv || (ov == bv && oq < bq)) { bv = ov; bq = oq; }
    }
    bq = __shfl(bq, 0, 64);
    if (lane == 0) lists[(b * GG + col) * TOPC + pass] = (short)bq;
    if ((bq & 63) == lane) rm |= (1u << (bq >> 6));
  }
}

// ---------------------------------------------------------------------------
// K2b: serial per-batch loop. Setup/teardown use 256 threads; the iterative
// loop runs entirely in wave 0 (wave-synchronous, ZERO barriers): matched
// ballot over per-gt counts, 4-column-parallel candidate walk via 16-lane
// subgroups, adds, added-list dedup. Writes ids and scatters the 1.0 entries
// directly into the (pre-zeroed) matching output.
// ---------------------------------------------------------------------------
__global__ __launch_bounds__(256) void serial_kernel(
    const float* __restrict__ cost, const short* __restrict__ lists,
    const int* __restrict__ dynks, const int* __restrict__ rowarg,
    float* __restrict__ out_match, float* __restrict__ out_ids) {
#pragma clang fp contract(off)
  const int b = blockIdx.x;
  const int tid = threadIdx.x;

  __shared__ unsigned s_mlo[QQ], s_mhi[QQ];
  __shared__ int s_first[QQ];
  __shared__ int s_pushed[QQ];
  __shared__ short s_rarg[QQ];
  __shared__ short s_list[GG * TOPC];
  __shared__ int s_cnt[GG];
  __shared__ short s_chosen[GG];
  __shared__ unsigned long long s_pack[GG];
  __shared__ int s_added[GG];
  __shared__ short s_ucols[GG];
  __shared__ short s_fb[GG];
  __shared__ int s_nadd, s_nfb, s_Tv;

  for (int q = tid; q < QQ; q += 256) {
    s_mlo[q] = 0u; s_mhi[q] = 0u; s_first[q] = -1; s_pushed[q] = -1;
    s_rarg[q] = (short)rowarg[b * QQ + q];
  }
  for (int i = tid; i < GG * TOPC; i += 256) s_list[i] = lists[b * GG * TOPC + i];
  if (tid < GG) s_cnt[tid] = 0;
  __syncthreads();

  // initial matching: first dynk list entries per column
  if (tid < GG) {
    int dynk = dynks[b * GG + tid];
    s_cnt[tid] = dynk;
    for (int i = 0; i < dynk; ++i) {
      int q = s_list[tid * TOPC + i];
      if (tid < 32) atomicOr(&s_mlo[q], 1u << tid);
      else          atomicOr(&s_mhi[q], 1u << (tid - 32));
      s_first[q] = 0;                    // benign same-value race
    }
  }
  __syncthreads();

  // initial dedup: strip over-queries to one-hot at row argmin
  for (int q = tid; q < QQ; q += 256) {
    unsigned lo = s_mlo[q], hi = s_mhi[q];
    if (__popc(lo) + __popc(hi) > 1) {
      int bg = s_rarg[q];
      unsigned tl = lo, th = hi;
      while (tl) { int g = __ffs(tl) - 1; tl &= tl - 1; if (g != bg) atomicSub(&s_cnt[g], 1); }
      while (th) { int g = __ffs(th) + 31; th &= th - 1; if (g != bg) atomicSub(&s_cnt[g], 1); }
      bool had = (bg < 32) ? ((lo >> bg) & 1u) : ((hi >> (bg - 32)) & 1u);
      if (!had) atomicAdd(&s_cnt[bg], 1);
      s_mlo[q] = (bg < 32) ? (1u << bg) : 0u;
      s_mhi[q] = (bg >= 32) ? (1u << (bg - 32)) : 0u;
    }
  }
  __syncthreads();

  const float* costb = cost + (size_t)b * GG * QQ;

  // ======== single-wave loop: zero barriers ========
  if (tid < 64) {
    const int lane = tid;
    int T = 0;
    for (int iter = 0; iter < GG; ++iter) {
      unsigned long long bal = __ballot(s_cnt[lane] > 0);  // matched cols
      unsigned long long um = ~bal;                        // unmatched cols
      if (um == 0ull) break;
      T++;

      // compact unmatched col list (wave-parallel prefix via popcount)
      bool isun = (um >> lane) & 1ull;
      int nu = __popcll(um);
      int pos = __popcll(um & ((1ull << lane) - 1ull));
      if (isun) s_ucols[pos] = (short)lane;
      if (lane == 0) { s_nfb = 0; s_nadd = 0; }

      // candidate walk: 4 cols at a time, 16-lane subgroups
      const int sg = lane >> 4, li = lane & 15;
      for (int base = 0; base < nu; base += 4) {
        int ci = base + sg;
        int col = (ci < nu) ? (int)s_ucols[ci] : -1;
        bool cand_un = false; int cq = 0;
        if (col >= 0) {
          cq = s_list[col * TOPC + li];
          cand_un = ((s_mlo[cq] | s_mhi[cq]) == 0u);
        }
        unsigned long long bb = __ballot(cand_un);
        unsigned sub = (unsigned)((bb >> (sg * 16)) & 0xFFFFull);
        if (col >= 0) {
          if (sub) {
            if (li == __ffs(sub) - 1) s_chosen[col] = (short)cq;
          } else if (li == 0) {
            int slot = atomicAdd(&s_nfb, 1);
            s_fb[slot] = (short)col;
          }
        }
      }

      // fallbacks: full-wave global scans (rare)
      int nfb = s_nfb;
      for (int fi = 0; fi < nfb; ++fi) {
        int col = s_fb[fi];
        const float* ccol = costb + (size_t)col * QQ;
        float bv = INFINITY; int bq = 0x7fffffff;
        for (int q2 = lane; q2 < QQ; q2 += 64) {
          if ((s_mlo[q2] | s_mhi[q2]) == 0u) {
            float cv = ccol[q2];
            if (cv < bv) { bv = cv; bq = q2; }
          }
        }
        for (int off = 32; off; off >>= 1) {
          float ov = __shfl_down(bv, off, 64); int oq = __shfl_down(bq, off, 64);
          if (ov < bv || (ov == bv && oq < bq)) { bv = ov; bq = oq; }
        }
        bq = __shfl(bq, 0, 64);
        if (bq == 0x7fffffff) {
          // all queries matched (pathological): exact penalized argmin
          bv = INFINITY; bq = 0x7fffffff;
          for (int q2 = lane; q2 < QQ; q2 += 64) {
            float cv = ccol[q2];
            int k = (s_first[q2] >= 0) ? (iter + 1 - s_first[q2]) : 0;
            for (int tt = 0; tt < k; ++tt) cv += 1e5f;
            if (cv < bv) { bv = cv; bq = q2; }
          }
          for (int off = 32; off; off >>= 1) {
            float ov = __shfl_down(bv, off, 64); int oq = __shfl_down(bq, off, 64);
            if (ov < bv || (ov == bv && oq < bq)) { bv = ov; bq = oq; }
          }
          bq = __shfl(bq, 0, 64);
        }
        if (lane == 0) s_chosen[col] = (short)bq;
      }

      // adds (lane == col; only cols unmatched at iteration start)
      if (isun) {
        int q = s_chosen[lane];
        if (lane < 32) atomicOr(&s_mlo[q], 1u << lane);
        else           atomicOr(&s_mhi[q], 1u << (lane - 32));
        atomicAdd(&s_cnt[lane], 1);
        if (s_first[q] == -1) s_first[q] = iter + 1;   // same-value race ok
        if (atomicExch(&s_pushed[q], iter) != iter) {  // dedupe pushes
          int slot = atomicAdd(&s_nadd, 1);
          s_added[slot] = q;
        }
      }

      // dedup just-added queries (<=64, all in this wave)
      int na = s_nadd;
      if (lane < na) {
        int q = s_added[lane];
        unsigned lo = s_mlo[q], hi = s_mhi[q];
        if (__popc(lo) + __popc(hi) > 1) {
          int bg = s_rarg[q];
          unsigned tl = lo, th = hi;
          while (tl) { int g = __ffs(tl) - 1; tl &= tl - 1; if (g != bg) atomicSub(&s_cnt[g], 1); }
          while (th) { int g = __ffs(th) + 31; th &= th - 1; if (g != bg) atomicSub(&s_cnt[g], 1); }
          bool had = (bg < 32) ? ((lo >> bg) & 1u) : ((hi >> (bg - 32)) & 1u);
          if (!had) atomicAdd(&s_cnt[bg], 1);
          s_mlo[q] = (bg < 32) ? (1u << bg) : 0u;
          s_mhi[q] = (bg >= 32) ? (1u << (bg - 32)) : 0u;
        }
      }
    }
    if (tid == 0) s_Tv = T;
  }
  __syncthreads();
  const int T = s_Tv;

  // final ids: scatter-argmin over matched queries with exact penalty replay
  if (tid < GG) s_pack[tid] = 0xFFFFFFFFFFFFFFFFull;
  __syncthreads();
  for (int q = tid; q < QQ; q += 256) {
    unsigned lo = s_mlo[q], hi = s_mhi[q];
    if (lo | hi) {
      int g = lo ? (__ffs(lo) - 1) : (__ffs(hi) + 31);
      float cv = costb[(size_t)g * QQ + q];
      int k = T - s_first[q];
      for (int tt = 0; tt < k; ++tt) cv += 1e5f;
      unsigned ub = __float_as_uint(cv);
      ub = (ub & 0x80000000u) ? ~ub : (ub | 0x80000000u);
      unsigned long long pk = ((unsigned long long)ub << 16) | (unsigned)q;
      atomicMin(&s_pack[g], pk);
    }
  }
  __syncthreads();
  if (tid < GG) {
    unsigned long long pk = s_pack[tid];
    out_ids[b * GG + tid] =
        (pk == 0xFFFFFFFFFFFFFFFFull) ? 0.0f : (float)(pk & 0xFFFFull);
  }
  // scatter the ones into the pre-zeroed matching output
  for (int q = tid; q < QQ; q += 256) {
    unsigned lo = s_mlo[q], hi = s_mhi[q];
    if (lo | hi) {
      int g = lo ? (__ffs(lo) - 1) : (__ffs(hi) + 31);
      out_match[((size_t)b * QQ + q) * GG + g] = 1.0f;
    }
  }
}

extern "C" void kernel_launch(void* const* d_in, const int* in_sizes, int n_in,
                              void* d_out, int out_size, void* d_ws, size_t ws_size,
                              hipStream_t stream) {
  const float* logits = (const float*)d_in[0];
  const float* boxes  = (const float*)d_in[1];
  const int*   gtc    = (const int*)d_in[2];
  const float* gtbx   = (const float*)d_in[3];
  const float* szout  = (const float*)d_in[4];
  const float* sztgt  = (const float*)d_in[5];
  float* out = (float*)d_out;

  const size_t matchN  = (size_t)BB * QQ * GG;     // floats (output 0)
  const size_t rowargN = (size_t)BB * QQ;          // ints
  const size_t listsN  = (size_t)BB * GG * TOPC;   // shorts
  const size_t dynksN  = (size_t)BB * GG;          // ints

  char* p = (char*)d_ws;
  float* cost   = (float*)p;          p += matchN * 4;   // 16.4 MB (ws is ~268MB)
  int*   rowarg = (int*)p;            p += rowargN * 4;
  short* lists  = (short*)p;          p += listsN * 2;
  int*   dynks  = (int*)p;

  float* out_ids = out + matchN;

  hipLaunchKernelGGL(cost_kernel, dim3(32, BB), dim3(256), 0, stream,
                     logits, boxes, gtc, gtbx, szout, sztgt, cost, rowarg, out);
  hipLaunchKernelGGL(pick_kernel, dim3(BB * GG / 4), dim3(256), 0, stream,
                     boxes, gtbx, cost, lists, dynks);
  hipLaunchKernelGGL(serial_kernel, dim3(BB), dim3(256), 0, stream,
                     cost, lists, dynks, rowarg, out, out_ids);
}